// Round 16
// baseline (2224.738 us; speedup 1.0000x reference)
//
#include <hip/hip_runtime.h>

using f16x8 = __attribute__((ext_vector_type(8))) _Float16;
using f16x4 = __attribute__((ext_vector_type(4))) _Float16;
using f32x4 = __attribute__((ext_vector_type(4))) float;
using u16 = unsigned short;
using u32 = unsigned int;

// ---------- helpers ----------
__device__ __forceinline__ u16 f2h(float f) {           // RNE f32->fp16 (v_cvt)
  union { _Float16 h; u16 u; } c;
  c.h = (_Float16)f;
  return c.u;
}
__device__ __forceinline__ uint4 pack8(const u16* h) {
  uint4 r;
  r.x = (u32)h[0] | ((u32)h[1] << 16);
  r.y = (u32)h[2] | ((u32)h[3] << 16);
  r.z = (u32)h[4] | ((u32)h[5] << 16);
  r.w = (u32)h[6] | ((u32)h[7] << 16);
  return r;
}
__device__ __forceinline__ float gelu_fast(float x) {   // == 0.5x(1+tanh(u)) exactly
  float u2 = 1.5957691216057308f * (x + 0.044715f * x * x * x);  // 2u
  return x / (1.0f + __expf(-u2));
}
__device__ __forceinline__ void gload16(const void* g, void* l) {
  __builtin_amdgcn_global_load_lds(
      (const __attribute__((address_space(1))) void*)g,
      (__attribute__((address_space(3))) void*)l, 16, 0, 0);
}

// ---------- fused weight transposes: all four [R,C] f32 -> [C,R] fp16 ----------
// One launch, 2560 blocks: [0,256) Ww 512x512; [256,512) Wv 512x512;
// [512,1536) W1 512x2048; [1536,2560) W2 2048x512. Each block does a 32x32 tile.
__global__ __launch_bounds__(256) void transpose_all_kernel(
    const float* __restrict__ Ww, const float* __restrict__ Wv,
    const float* __restrict__ W1, const float* __restrict__ W2,
    u16* __restrict__ WwT, u16* __restrict__ WvT,
    u16* __restrict__ W1T, u16* __restrict__ W2T)
{
  __shared__ float t[32][33];
  int id = blockIdx.x;
  const float* in; u16* out; int R, C, bx, by;
  if (id < 256)        { in = Ww; out = WwT; R = 512;  C = 512;  bx = id & 15; by = id >> 4; }
  else if (id < 512)   { id -= 256;  in = Wv; out = WvT; R = 512;  C = 512;  bx = id & 15; by = id >> 4; }
  else if (id < 1536)  { id -= 512;  in = W1; out = W1T; R = 512;  C = 2048; bx = id & 63; by = id >> 6; }
  else                 { id -= 1536; in = W2; out = W2T; R = 2048; C = 512;  bx = id & 15; by = id >> 4; }
  const int lx = threadIdx.x & 31, ly = threadIdx.x >> 5;
  const int c0 = bx << 5, r0 = by << 5;
  for (int i = ly; i < 32; i += 8)
    t[i][lx] = in[(long)(r0 + i) * C + c0 + lx];
  __syncthreads();
  for (int i = ly; i < 32; i += 8)
    out[(long)(c0 + i) * R + r0 + lx] = f2h(t[lx][i]);
}

// ---------- LayerNorm over rows of 512 f32 -> fp16 ----------
__global__ __launch_bounds__(256) void ln_f16_kernel(
    const float* __restrict__ x, const float* __restrict__ gamma,
    const float* __restrict__ beta, u16* __restrict__ outH)
{
  const int row  = (blockIdx.x << 2) + (threadIdx.x >> 6);
  const int lane = threadIdx.x & 63;
  const float* xr = x + (long)row * 512 + lane * 8;
  float v[8];
  *(float4*)&v[0] = *(const float4*)xr;
  *(float4*)&v[4] = *(const float4*)(xr + 4);
  float s = 0.f;
#pragma unroll
  for (int j = 0; j < 8; ++j) s += v[j];
#pragma unroll
  for (int o = 32; o; o >>= 1) s += __shfl_xor(s, o);
  const float mu = s * (1.0f / 512.0f);
  float q = 0.f;
#pragma unroll
  for (int j = 0; j < 8; ++j) { float d = v[j] - mu; q += d * d; }
#pragma unroll
  for (int o = 32; o; o >>= 1) q += __shfl_xor(q, o);
  const float rs = rsqrtf(q * (1.0f / 512.0f) + 1e-5f);
  float gv[8], bv[8];
  *(float4*)&gv[0] = *(const float4*)(gamma + lane * 8);
  *(float4*)&gv[4] = *(const float4*)(gamma + lane * 8 + 4);
  *(float4*)&bv[0] = *(const float4*)(beta + lane * 8);
  *(float4*)&bv[4] = *(const float4*)(beta + lane * 8 + 4);
  u16 hs[8];
#pragma unroll
  for (int j = 0; j < 8; ++j)
    hs[j] = f2h((v[j] - mu) * rs * gv[j] + bv[j]);
  *(uint4*)(outH + (long)row * 512 + lane * 8) = pack8(hs);
}

// ---------- LayerNorm over rows of 512 fp16 -> fp16 ----------
__global__ __launch_bounds__(256) void ln_h16_kernel(
    const u16* __restrict__ x, const float* __restrict__ gamma,
    const float* __restrict__ beta, u16* __restrict__ outH)
{
  const int row  = (blockIdx.x << 2) + (threadIdx.x >> 6);
  const int lane = threadIdx.x & 63;
  const f16x8 x8 = *(const f16x8*)(x + (long)row * 512 + lane * 8);
  float v[8];
#pragma unroll
  for (int j = 0; j < 8; ++j) v[j] = (float)x8[j];
  float s = 0.f;
#pragma unroll
  for (int j = 0; j < 8; ++j) s += v[j];
#pragma unroll
  for (int o = 32; o; o >>= 1) s += __shfl_xor(s, o);
  const float mu = s * (1.0f / 512.0f);
  float q = 0.f;
#pragma unroll
  for (int j = 0; j < 8; ++j) { float d = v[j] - mu; q += d * d; }
#pragma unroll
  for (int o = 32; o; o >>= 1) q += __shfl_xor(q, o);
  const float rs = rsqrtf(q * (1.0f / 512.0f) + 1e-5f);
  float gv[8], bv[8];
  *(float4*)&gv[0] = *(const float4*)(gamma + lane * 8);
  *(float4*)&gv[4] = *(const float4*)(gamma + lane * 8 + 4);
  *(float4*)&bv[0] = *(const float4*)(beta + lane * 8);
  *(float4*)&bv[4] = *(const float4*)(beta + lane * 8 + 4);
  u16 hs[8];
#pragma unroll
  for (int j = 0; j < 8; ++j)
    hs[j] = f2h((v[j] - mu) * rs * gv[j] + bv[j]);
  *(uint4*)(outH + (long)row * 512 + lane * 8) = pack8(hs);
}

// ---------- row softmax over 512 fp16 -> fp16 ----------
__global__ __launch_bounds__(256) void softmax_f16_kernel(
    const u16* __restrict__ scores, u16* __restrict__ attn)
{
  const int row  = (blockIdx.x << 2) + (threadIdx.x >> 6);
  const int lane = threadIdx.x & 63;
  const f16x8 v8 = *(const f16x8*)(scores + (long)row * 512 + lane * 8);
  float v[8];
#pragma unroll
  for (int j = 0; j < 8; ++j) v[j] = (float)v8[j];
  float m = v[0];
#pragma unroll
  for (int j = 1; j < 8; ++j) m = fmaxf(m, v[j]);
#pragma unroll
  for (int o = 32; o; o >>= 1) m = fmaxf(m, __shfl_xor(m, o));
  float e[8], s = 0.f;
#pragma unroll
  for (int j = 0; j < 8; ++j) { e[j] = __expf(v[j] - m); s += e[j]; }
#pragma unroll
  for (int o = 32; o; o >>= 1) s += __shfl_xor(s, o);
  const float inv = 1.0f / s;
  u16 h[8];
#pragma unroll
  for (int j = 0; j < 8; ++j) h[j] = f2h(e[j] * inv);
  *(uint4*)(attn + (long)row * 512 + lane * 8) = pack8(h);
}

// ---------- 256x256 16-wave NT GEMM, BK=32, fp16 — 2 blocks/CU ----------
// C[m,n] = sum_k A[m,k]*B[n,k]. K in NT tiles of 32; tile t uses part (t>>4)
// (parts are 1024B of K-row = 16 tiles; same pointers/strides as BK=64 build).
// CHANGE vs r15: BK 64->32 halves LDS to 64KB -> 2 blocks/CU co-resident
// (32 waves/CU, 8/SIMD — the max). Cross-BLOCK wave overlap (m114/m97
// mechanism) hides the per-tile barrier drain that intra-block scheduling
// couldn't (15 variants pinned at 17-29% MfmaUtil at 1 block/CU).
// __launch_bounds__(1024, 8) pins VGPR<=64 so 2 blocks are guaranteed.
// LDS 64KB: A(d) at d*16384 (256 rows x 64B), B(d) at 32768 + d*16384.
// Swizzle for 64B rows: slot' = slot ^ (row&3) (2-way bank conflict = free);
// applied via pre-swizzled global source + swizzled ds_read.
// Per tile: 2 gload16/thread (A+B), 8 ds_read_b128, 16 MFMA, 1 barrier.
// XCD-chunked block swizzle; swapped-operand MFMA -> wide stores.
// EPI: 0 fp16 sqrt(v^2+eps); 4 fp16 gelu(v+bias); 6 fp16, plain if
//      blockN<512 else sqrt(v^2+eps) [merged proj|vx]; 7 fp16(resid_f32+v);
//      8 f32 resid16(fp16)+v+bias [final out].
template<int EPI>
__global__ __launch_bounds__(1024, 8) void gemm8(
    const char* A0, const char* A1, const char* A2, const char* A3,
    const char* B0, const char* B1, const char* B2, const char* B3,
    int N, int NT, int ldAb, int ldBb,
    long sAb, long sBb, long sC,
    float* __restrict__ outF, u16* __restrict__ outU,
    const float* __restrict__ resid, const u16* __restrict__ residH,
    const float* __restrict__ bias)
{
  __shared__ __align__(16) char lds[65536];
  const int tid = threadIdx.x;
  const int w = tid >> 6, l = tid & 63;
  const int wm = w >> 2, wn = w & 3;

  // XCD-chunked block swizzle (total %8 == 0 for all our launches)
  const int gx = gridDim.x, gy = gridDim.y;
  int flat = ((int)blockIdx.z * gy + (int)blockIdx.y) * gx + (int)blockIdx.x;
  const int total = gx * gy * (int)gridDim.z;
  flat = (flat & 7) * (total >> 3) + (flat >> 3);
  const int bx = flat % gx;
  int rem = flat / gx;
  const int by = rem % gy, bz = rem / gy;

  const long blockM = (long)by * 256;
  const long blockN = (long)bx * 256;
  const long za = (long)bz * sAb;
  const long zb = (long)bz * sBb;
  const char* a0p = A0 + za; const char* a1p = A1 + za;
  const char* a2p = A2 + za; const char* a3p = A3 + za;
  const char* b0p = B0 + zb; const char* b1p = B1 + zb;
  const char* b2p = B2 + zb; const char* b3p = B3 + zb;

  auto partA = [&](int t) { return t < 16 ? a0p : t < 32 ? a1p : t < 48 ? a2p : a3p; };
  auto partB = [&](int t) { return t < 16 ? b0p : t < 32 ? b1p : t < 48 ? b2p : b3p; };

  // staging: thread tid covers row tid>>2 (0..255), dest slot tid&3 (16B);
  // global source slot pre-swizzled: (tid&3)^((tid>>2)&3) so LDS-linear dest
  // holds LDS[r][s] = G[r][s ^ (r&3)].
  const long stgSw = ((tid & 3) ^ ((tid >> 2) & 3)) << 4;
  const long raA = (blockM + (tid >> 2)) * (long)ldAb + stgSw;
  const long raB = (blockN + (tid >> 2)) * (long)ldBb + stgSw;
  auto stageA = [&](int t) {
    const char* s = partA(t) + (((long)(t & 15)) << 6) + raA;
    gload16(s, lds + ((t & 1) << 14) + (tid << 4));
  };
  auto stageB = [&](int t) {
    const char* s = partB(t) + (((long)(t & 15)) << 6) + raB;
    gload16(s, lds + 32768 + ((t & 1) << 14) + (tid << 4));
  };

  f32x4 acc[4][4];
#pragma unroll
  for (int i = 0; i < 4; ++i)
#pragma unroll
    for (int j = 0; j < 4; ++j) acc[i][j] = (f32x4){0.f, 0.f, 0.f, 0.f};

  const int lr = l & 15, kg = l >> 4;
  // fragment read: row = wm*64 + mf*16 + lr (byte row*64); slot kg swizzled
  // by row&3 == lr&3 -> per-lane byte offset:
  const int po = (lr << 6) + (((kg ^ (lr & 3))) << 4);
  const char* aL = lds + (wm << 12);           // + d<<14 + mf<<10 + po
  const char* bL = lds + 32768 + (wn << 12);   // + d<<14 + nf<<10 + po

  f16x8 a[4], b[4];
  auto readA = [&](const char* p) {
#pragma unroll
    for (int mf = 0; mf < 4; ++mf) a[mf] = *(const f16x8*)(p + (mf << 10));
  };
  auto readB = [&](const char* p) {
#pragma unroll
    for (int nf = 0; nf < 4; ++nf) b[nf] = *(const f16x8*)(p + (nf << 10));
  };

#define MFMA16()                                                              \
  do {                                                                        \
    _Pragma("unroll")                                                         \
    for (int mf = 0; mf < 4; ++mf)                                            \
      _Pragma("unroll")                                                       \
      for (int nf = 0; nf < 4; ++nf)                                          \
        acc[mf][nf] = __builtin_amdgcn_mfma_f32_16x16x32_f16(                 \
            b[nf], a[mf], acc[mf][nf], 0, 0, 0);                              \
  } while (0)

  // prologue: stage tile 0
  stageA(0); stageB(0);
  __syncthreads();

  for (int t = 0; t < NT; ++t) {
    const int d = t & 1;
    if (t + 1 < NT) { stageA(t + 1); stageB(t + 1); }
    readA(aL + (d << 14) + po);
    readB(bL + (d << 14) + po);
    MFMA16();
    if (t + 1 < NT) __syncthreads();
  }
#undef MFMA16

  // ---- epilogue (swapped layout): m = ..+lr, n = ..+kg*4+r -> wide stores
  const long cb = (long)bz * sC;
  const int m0 = (int)blockM + wm * 64 + lr;
  const int n0 = (int)blockN + wn * 64 + (kg << 2);
  const bool vabs = (blockN >= 512);   // for EPI 6 (merged proj|vx)
#pragma unroll
  for (int mi = 0; mi < 4; ++mi)
#pragma unroll
    for (int ni = 0; ni < 4; ++ni) {
      const int m = m0 + (mi << 4);
      const int n = n0 + (ni << 4);
      const long idx = cb + (long)m * N + n;
      f32x4 v = acc[mi][ni];
      if (EPI == 0) {
        union { u16 h[4]; uint2 u; } p;
#pragma unroll
        for (int r = 0; r < 4; ++r) p.h[r] = f2h(sqrtf(v[r] * v[r] + 1e-8f));
        *(uint2*)(outU + idx) = p.u;
      } else if (EPI == 4) {
        f32x4 bb = *(const f32x4*)(bias + n);
        union { u16 h[4]; uint2 u; } p;
#pragma unroll
        for (int r = 0; r < 4; ++r) p.h[r] = f2h(gelu_fast(v[r] + bb[r]));
        *(uint2*)(outU + idx) = p.u;
      } else if (EPI == 6) {  // merged proj|vx
        union { u16 h[4]; uint2 u; } p;
#pragma unroll
        for (int r = 0; r < 4; ++r)
          p.h[r] = f2h(vabs ? sqrtf(v[r] * v[r] + 1e-8f) : v[r]);
        *(uint2*)(outU + idx) = p.u;
      } else if (EPI == 7) {  // x1 = resid(f32) + v -> fp16
        f32x4 rd = *(const f32x4*)(resid + idx);
        union { u16 h[4]; uint2 u; } p;
#pragma unroll
        for (int r = 0; r < 4; ++r) p.h[r] = f2h(rd[r] + v[r]);
        *(uint2*)(outU + idx) = p.u;
      } else {                // EPI == 8: out = resid16(fp16) + v + bias -> f32
        f16x4 rh = *(const f16x4*)(residH + idx);
        f32x4 bb = *(const f32x4*)(bias + n);
        f32x4 o;
#pragma unroll
        for (int r = 0; r < 4; ++r) o[r] = (float)rh[r] + v[r] + bb[r];
        *(f32x4*)(outF + idx) = o;
      }
    }
}

// ---------- launch ----------
extern "C" void kernel_launch(void* const* d_in, const int* in_sizes, int n_in,
                              void* d_out, int out_size, void* d_ws, size_t ws_size,
                              hipStream_t stream)
{
  const float* x   = (const float*)d_in[0];
  const float* g1  = (const float*)d_in[1];
  const float* be1 = (const float*)d_in[2];
  const float* Wv  = (const float*)d_in[3];
  const float* Ww  = (const float*)d_in[4];
  const float* g2  = (const float*)d_in[5];
  const float* be2 = (const float*)d_in[6];
  const float* W1  = (const float*)d_in[7];
  const float* b1  = (const float*)d_in[8];
  const float* W2  = (const float*)d_in[9];
  const float* b2  = (const float*)d_in[10];
  float* out = (float*)d_out;

  char* ws = (char*)d_ws;
  // B=64, T=E=512, H=2048, M=B*T=32768. fp16 single-pass everywhere;
  // x1 kept in fp16 (error <= 6*2^-11 ~ 0.003, directly on output).
  u16* inp     = (u16*)(ws);                 // [0,32M)    LN1 -> pvx/scores
  u16* pvx     = (u16*)(ws + 33554432);      // [32,96M)   proj cols 0-511 | vx 512-1023 (ld 2048B)
  u16* scores16= (u16*)(ws + 100663296);     // [96,128M)  fp16 logits
  u16* attn    = (u16*)(ws + 134217728);     // [128,160M) softmax out
  u16* x1h     = (u16*)(ws + 167772160);     // [160,192M) fp16 x1 (lives to end)
  u16* h_in    = inp;                        // alias: written after inp dead
  u16* h_mid   = (u16*)(ws + 33554432);      // [32,160M): pvx/scores/attn dead by MLP1
  char* wb = ws + 201326592;                 // weights live whole run
  u16* WwT = (u16*)(wb);                     // rows 0-511 of merged B
  u16* WvT = (u16*)(wb + 524288);            // rows 512-1023 (contiguous)
  u16* W1T = (u16*)(wb + 1048576);
  u16* W2T = (u16*)(wb + 3145728);
  // total ws used: ~198 MB

  // all four weight transposes in ONE launch (f32 -> fp16, K-contiguous)
  transpose_all_kernel<<<2560, 256, 0, stream>>>(
      Ww, Wv, W1, W2, WwT, WvT, W1T, W2T);

  // LN1: x -> inp fp16
  ln_f16_kernel<<<8192, 256, 0, stream>>>(x, g1, be1, inp);

  // pvx = inp @ [Ww | Wv]  (N=1024; cols<512 plain -> proj, >=512 |.| -> vx)
  gemm8<6><<<dim3(4, 128, 1), 1024, 0, stream>>>(
      (const char*)inp, (const char*)inp, (const char*)inp, (const char*)inp,
      (const char*)WwT, (const char*)WwT, (const char*)WwT, (const char*)WwT,
      1024, 16, 1024, 1024, 0, 0, 0,
      nullptr, pvx, nullptr, nullptr, nullptr);

  // scores16[b,i,j] = sqrt((proj_i . inp_j)^2+eps) -> fp16 (batched)
  gemm8<0><<<dim3(2, 2, 64), 1024, 0, stream>>>(
      (const char*)pvx, (const char*)pvx, (const char*)pvx, (const char*)pvx,
      (const char*)inp, (const char*)inp, (const char*)inp, (const char*)inp,
      512, 16, 2048, 1024, 1048576, 524288, 262144,
      nullptr, scores16, nullptr, nullptr, nullptr);

  // softmax rows (fp16 in) -> attn fp16
  softmax_f16_kernel<<<8192, 256, 0, stream>>>(scores16, attn);

  // x1 = x + attn@vx^T -> x1h fp16 (batched; vx = pvx cols 512+)
  gemm8<7><<<dim3(2, 2, 64), 1024, 0, stream>>>(
      (const char*)attn, (const char*)attn, (const char*)attn, (const char*)attn,
      (const char*)pvx + 1024, (const char*)pvx + 1024, (const char*)pvx + 1024, (const char*)pvx + 1024,
      512, 16, 1024, 2048, 524288, 1048576, 262144,
      nullptr, x1h, x, nullptr, nullptr);

  // LN2: x1h (fp16) -> h_in fp16 (into dead inp)
  ln_h16_kernel<<<8192, 256, 0, stream>>>(x1h, g2, be2, h_in);

  // h_mid = gelu(h_in@W1 + b1) fp16
  gemm8<4><<<dim3(8, 128, 1), 1024, 0, stream>>>(
      (const char*)h_in, (const char*)h_in, (const char*)h_in, (const char*)h_in,
      (const char*)W1T, (const char*)W1T, (const char*)W1T, (const char*)W1T,
      2048, 16, 1024, 1024, 0, 0, 0,
      nullptr, h_mid, nullptr, nullptr, b1);

  // out = x1h + h_mid@W2 + b2  (K=2048 via 4 contiguous 1024B parts) -> f32
  gemm8<8><<<dim3(2, 128, 1), 1024, 0, stream>>>(
      (const char*)h_mid, (const char*)h_mid + 1024, (const char*)h_mid + 2048, (const char*)h_mid + 3072,
      (const char*)W2T, (const char*)W2T + 1024, (const char*)W2T + 2048, (const char*)W2T + 3072,
      512, 64, 4096, 4096, 0, 0, 0,
      out, nullptr, nullptr, x1h, b2);
}

// Round 17
// 381.030 us; speedup vs baseline: 5.8387x; 5.8387x over previous
//
#include <hip/hip_runtime.h>

using f16x8 = __attribute__((ext_vector_type(8))) _Float16;
using f16x4 = __attribute__((ext_vector_type(4))) _Float16;
using f32x4 = __attribute__((ext_vector_type(4))) float;
using u16 = unsigned short;
using u32 = unsigned int;

// ---------- helpers ----------
__device__ __forceinline__ u16 f2h(float f) {           // RNE f32->fp16 (v_cvt)
  union { _Float16 h; u16 u; } c;
  c.h = (_Float16)f;
  return c.u;
}
__device__ __forceinline__ uint4 pack8(const u16* h) {
  uint4 r;
  r.x = (u32)h[0] | ((u32)h[1] << 16);
  r.y = (u32)h[2] | ((u32)h[3] << 16);
  r.z = (u32)h[4] | ((u32)h[5] << 16);
  r.w = (u32)h[6] | ((u32)h[7] << 16);
  return r;
}
__device__ __forceinline__ float gelu_fast(float x) {   // == 0.5x(1+tanh(u)) exactly
  float u2 = 1.5957691216057308f * (x + 0.044715f * x * x * x);  // 2u
  return x / (1.0f + __expf(-u2));
}
__device__ __forceinline__ void gload16(const void* g, void* l) {
  __builtin_amdgcn_global_load_lds(
      (const __attribute__((address_space(1))) void*)g,
      (__attribute__((address_space(3))) void*)l, 16, 0, 0);
}

// ---------- fused weight transposes: all four [R,C] f32 -> [C,R] fp16 ----------
__global__ __launch_bounds__(256) void transpose_all_kernel(
    const float* __restrict__ Ww, const float* __restrict__ Wv,
    const float* __restrict__ W1, const float* __restrict__ W2,
    u16* __restrict__ WwT, u16* __restrict__ WvT,
    u16* __restrict__ W1T, u16* __restrict__ W2T)
{
  __shared__ float t[32][33];
  int id = blockIdx.x;
  const float* in; u16* out; int R, C, bx, by;
  if (id < 256)        { in = Ww; out = WwT; R = 512;  C = 512;  bx = id & 15; by = id >> 4; }
  else if (id < 512)   { id -= 256;  in = Wv; out = WvT; R = 512;  C = 512;  bx = id & 15; by = id >> 4; }
  else if (id < 1536)  { id -= 512;  in = W1; out = W1T; R = 512;  C = 2048; bx = id & 63; by = id >> 6; }
  else                 { id -= 1536; in = W2; out = W2T; R = 2048; C = 512;  bx = id & 15; by = id >> 4; }
  const int lx = threadIdx.x & 31, ly = threadIdx.x >> 5;
  const int c0 = bx << 5, r0 = by << 5;
  for (int i = ly; i < 32; i += 8)
    t[i][lx] = in[(long)(r0 + i) * C + c0 + lx];
  __syncthreads();
  for (int i = ly; i < 32; i += 8)
    out[(long)(c0 + i) * R + r0 + lx] = f2h(t[lx][i]);
}

// ---------- LayerNorm over rows of 512 f32 -> fp16 ----------
__global__ __launch_bounds__(256) void ln_f16_kernel(
    const float* __restrict__ x, const float* __restrict__ gamma,
    const float* __restrict__ beta, u16* __restrict__ outH)
{
  const int row  = (blockIdx.x << 2) + (threadIdx.x >> 6);
  const int lane = threadIdx.x & 63;
  const float* xr = x + (long)row * 512 + lane * 8;
  float v[8];
  *(float4*)&v[0] = *(const float4*)xr;
  *(float4*)&v[4] = *(const float4*)(xr + 4);
  float s = 0.f;
#pragma unroll
  for (int j = 0; j < 8; ++j) s += v[j];
#pragma unroll
  for (int o = 32; o; o >>= 1) s += __shfl_xor(s, o);
  const float mu = s * (1.0f / 512.0f);
  float q = 0.f;
#pragma unroll
  for (int j = 0; j < 8; ++j) { float d = v[j] - mu; q += d * d; }
#pragma unroll
  for (int o = 32; o; o >>= 1) q += __shfl_xor(q, o);
  const float rs = rsqrtf(q * (1.0f / 512.0f) + 1e-5f);
  float gv[8], bv[8];
  *(float4*)&gv[0] = *(const float4*)(gamma + lane * 8);
  *(float4*)&gv[4] = *(const float4*)(gamma + lane * 8 + 4);
  *(float4*)&bv[0] = *(const float4*)(beta + lane * 8);
  *(float4*)&bv[4] = *(const float4*)(beta + lane * 8 + 4);
  u16 hs[8];
#pragma unroll
  for (int j = 0; j < 8; ++j)
    hs[j] = f2h((v[j] - mu) * rs * gv[j] + bv[j]);
  *(uint4*)(outH + (long)row * 512 + lane * 8) = pack8(hs);
}

// ---------- LayerNorm over rows of 512 fp16 -> fp16 ----------
__global__ __launch_bounds__(256) void ln_h16_kernel(
    const u16* __restrict__ x, const float* __restrict__ gamma,
    const float* __restrict__ beta, u16* __restrict__ outH)
{
  const int row  = (blockIdx.x << 2) + (threadIdx.x >> 6);
  const int lane = threadIdx.x & 63;
  const f16x8 x8 = *(const f16x8*)(x + (long)row * 512 + lane * 8);
  float v[8];
#pragma unroll
  for (int j = 0; j < 8; ++j) v[j] = (float)x8[j];
  float s = 0.f;
#pragma unroll
  for (int j = 0; j < 8; ++j) s += v[j];
#pragma unroll
  for (int o = 32; o; o >>= 1) s += __shfl_xor(s, o);
  const float mu = s * (1.0f / 512.0f);
  float q = 0.f;
#pragma unroll
  for (int j = 0; j < 8; ++j) { float d = v[j] - mu; q += d * d; }
#pragma unroll
  for (int o = 32; o; o >>= 1) q += __shfl_xor(q, o);
  const float rs = rsqrtf(q * (1.0f / 512.0f) + 1e-5f);
  float gv[8], bv[8];
  *(float4*)&gv[0] = *(const float4*)(gamma + lane * 8);
  *(float4*)&gv[4] = *(const float4*)(gamma + lane * 8 + 4);
  *(float4*)&bv[0] = *(const float4*)(beta + lane * 8);
  *(float4*)&bv[4] = *(const float4*)(beta + lane * 8 + 4);
  u16 hs[8];
#pragma unroll
  for (int j = 0; j < 8; ++j)
    hs[j] = f2h((v[j] - mu) * rs * gv[j] + bv[j]);
  *(uint4*)(outH + (long)row * 512 + lane * 8) = pack8(hs);
}

// ---------- row softmax over 512 fp16 -> fp16 ----------
__global__ __launch_bounds__(256) void softmax_f16_kernel(
    const u16* __restrict__ scores, u16* __restrict__ attn)
{
  const int row  = (blockIdx.x << 2) + (threadIdx.x >> 6);
  const int lane = threadIdx.x & 63;
  const f16x8 v8 = *(const f16x8*)(scores + (long)row * 512 + lane * 8);
  float v[8];
#pragma unroll
  for (int j = 0; j < 8; ++j) v[j] = (float)v8[j];
  float m = v[0];
#pragma unroll
  for (int j = 1; j < 8; ++j) m = fmaxf(m, v[j]);
#pragma unroll
  for (int o = 32; o; o >>= 1) m = fmaxf(m, __shfl_xor(m, o));
  float e[8], s = 0.f;
#pragma unroll
  for (int j = 0; j < 8; ++j) { e[j] = __expf(v[j] - m); s += e[j]; }
#pragma unroll
  for (int o = 32; o; o >>= 1) s += __shfl_xor(s, o);
  const float inv = 1.0f / s;
  u16 h[8];
#pragma unroll
  for (int j = 0; j < 8; ++j) h[j] = f2h(e[j] * inv);
  *(uint4*)(attn + (long)row * 512 + lane * 8) = pack8(h);
}

// ---------- 256x256 16-wave NT GEMM, BK=32, fp16 — clean 2-blocks/CU test ----
// C[m,n] = sum_k A[m,k]*B[n,k]. K in NT tiles of 32; tile t uses part (t>>4)
// (parts are 1024B of K-row = 16 tiles).
// vs r16 (which was invalidated by reg-spill): (a) __launch_bounds__(1024)
// WITHOUT the min-waves pin — VGPR back to the measured 64; 2 blocks/CU fit
// exactly (LDS 2x64=128<=160KB, VGPR 2x16x64 = full 2048/CU pool);
// (b) CORRECTED 64B-row swizzle: s' = s ^ ((row>>2)&3). r16's s^(row&3) left
// rows {0,4,8,12} of each 16-row lane group on one bank (4-way, 8.4M
// conflicts); with (row>>2)&3 those rows get distinct slots; the residual
// 2-way (rows r,r+2 of each 4-group) is free (m136).
// LDS 64KB: A(d) at d*16384 (256 rows x 64B), B(d) at 32768 + d*16384.
// Per tile: 2 gload16/thread, 8 ds_read_b128, 16 MFMA, 1 barrier.
// XCD-chunked block swizzle; swapped-operand MFMA -> wide stores.
// EPI: 0 fp16 sqrt(v^2+eps); 4 fp16 gelu(v+bias); 6 merged proj|vx;
//      7 fp16(resid_f32+v); 8 f32 resid16(fp16)+v+bias.
template<int EPI>
__global__ __launch_bounds__(1024) void gemm8(
    const char* A0, const char* A1, const char* A2, const char* A3,
    const char* B0, const char* B1, const char* B2, const char* B3,
    int N, int NT, int ldAb, int ldBb,
    long sAb, long sBb, long sC,
    float* __restrict__ outF, u16* __restrict__ outU,
    const float* __restrict__ resid, const u16* __restrict__ residH,
    const float* __restrict__ bias)
{
  __shared__ __align__(16) char lds[65536];
  const int tid = threadIdx.x;
  const int w = tid >> 6, l = tid & 63;
  const int wm = w >> 2, wn = w & 3;

  // XCD-chunked block swizzle (total %8 == 0 for all our launches)
  const int gx = gridDim.x, gy = gridDim.y;
  int flat = ((int)blockIdx.z * gy + (int)blockIdx.y) * gx + (int)blockIdx.x;
  const int total = gx * gy * (int)gridDim.z;
  flat = (flat & 7) * (total >> 3) + (flat >> 3);
  const int bx = flat % gx;
  int rem = flat / gx;
  const int by = rem % gy, bz = rem / gy;

  const long blockM = (long)by * 256;
  const long blockN = (long)bx * 256;
  const long za = (long)bz * sAb;
  const long zb = (long)bz * sBb;
  const char* a0p = A0 + za; const char* a1p = A1 + za;
  const char* a2p = A2 + za; const char* a3p = A3 + za;
  const char* b0p = B0 + zb; const char* b1p = B1 + zb;
  const char* b2p = B2 + zb; const char* b3p = B3 + zb;

  auto partA = [&](int t) { return t < 16 ? a0p : t < 32 ? a1p : t < 48 ? a2p : a3p; };
  auto partB = [&](int t) { return t < 16 ? b0p : t < 32 ? b1p : t < 48 ? b2p : b3p; };

  // staging: thread tid covers row tid>>2 (0..255), dest slot tid&3 (16B);
  // source slot pre-swizzled: (tid&3)^((tid>>4)&3) = s ^ ((row>>2)&3) so the
  // LDS-linear dest holds LDS[r][s] = G[r][s ^ ((r>>2)&3)].
  const long stgSw = ((tid & 3) ^ ((tid >> 4) & 3)) << 4;
  const long raA = (blockM + (tid >> 2)) * (long)ldAb + stgSw;
  const long raB = (blockN + (tid >> 2)) * (long)ldBb + stgSw;
  auto stageA = [&](int t) {
    const char* s = partA(t) + (((long)(t & 15)) << 6) + raA;
    gload16(s, lds + ((t & 1) << 14) + (tid << 4));
  };
  auto stageB = [&](int t) {
    const char* s = partB(t) + (((long)(t & 15)) << 6) + raB;
    gload16(s, lds + 32768 + ((t & 1) << 14) + (tid << 4));
  };

  f32x4 acc[4][4];
#pragma unroll
  for (int i = 0; i < 4; ++i)
#pragma unroll
    for (int j = 0; j < 4; ++j) acc[i][j] = (f32x4){0.f, 0.f, 0.f, 0.f};

  const int lr = l & 15, kg = l >> 4;
  // fragment read: row = wm*64 + mf*16 + lr (byte row*64); (row>>2)&3 ==
  // (lr>>2)&3 (wm*64, mf*16 only touch bits >=4) -> per-lane byte offset:
  const int po = (lr << 6) + ((kg ^ ((lr >> 2) & 3)) << 4);
  const char* aL = lds + (wm << 12);           // + d<<14 + mf<<10 + po
  const char* bL = lds + 32768 + (wn << 12);   // + d<<14 + nf<<10 + po

  f16x8 a[4], b[4];
  auto readA = [&](const char* p) {
#pragma unroll
    for (int mf = 0; mf < 4; ++mf) a[mf] = *(const f16x8*)(p + (mf << 10));
  };
  auto readB = [&](const char* p) {
#pragma unroll
    for (int nf = 0; nf < 4; ++nf) b[nf] = *(const f16x8*)(p + (nf << 10));
  };

#define MFMA16()                                                              \
  do {                                                                        \
    _Pragma("unroll")                                                         \
    for (int mf = 0; mf < 4; ++mf)                                            \
      _Pragma("unroll")                                                       \
      for (int nf = 0; nf < 4; ++nf)                                          \
        acc[mf][nf] = __builtin_amdgcn_mfma_f32_16x16x32_f16(                 \
            b[nf], a[mf], acc[mf][nf], 0, 0, 0);                              \
  } while (0)

  // prologue: stage tile 0
  stageA(0); stageB(0);
  __syncthreads();

  for (int t = 0; t < NT; ++t) {
    const int d = t & 1;
    if (t + 1 < NT) { stageA(t + 1); stageB(t + 1); }
    readA(aL + (d << 14) + po);
    readB(bL + (d << 14) + po);
    MFMA16();
    if (t + 1 < NT) __syncthreads();
  }
#undef MFMA16

  // ---- epilogue (swapped layout): m = ..+lr, n = ..+kg*4+r -> wide stores
  const long cb = (long)bz * sC;
  const int m0 = (int)blockM + wm * 64 + lr;
  const int n0 = (int)blockN + wn * 64 + (kg << 2);
  const bool vabs = (blockN >= 512);   // for EPI 6 (merged proj|vx)
#pragma unroll
  for (int mi = 0; mi < 4; ++mi)
#pragma unroll
    for (int ni = 0; ni < 4; ++ni) {
      const int m = m0 + (mi << 4);
      const int n = n0 + (ni << 4);
      const long idx = cb + (long)m * N + n;
      f32x4 v = acc[mi][ni];
      if (EPI == 0) {
        union { u16 h[4]; uint2 u; } p;
#pragma unroll
        for (int r = 0; r < 4; ++r) p.h[r] = f2h(sqrtf(v[r] * v[r] + 1e-8f));
        *(uint2*)(outU + idx) = p.u;
      } else if (EPI == 4) {
        f32x4 bb = *(const f32x4*)(bias + n);
        union { u16 h[4]; uint2 u; } p;
#pragma unroll
        for (int r = 0; r < 4; ++r) p.h[r] = f2h(gelu_fast(v[r] + bb[r]));
        *(uint2*)(outU + idx) = p.u;
      } else if (EPI == 6) {  // merged proj|vx
        union { u16 h[4]; uint2 u; } p;
#pragma unroll
        for (int r = 0; r < 4; ++r)
          p.h[r] = f2h(vabs ? sqrtf(v[r] * v[r] + 1e-8f) : v[r]);
        *(uint2*)(outU + idx) = p.u;
      } else if (EPI == 7) {  // x1 = resid(f32) + v -> fp16
        f32x4 rd = *(const f32x4*)(resid + idx);
        union { u16 h[4]; uint2 u; } p;
#pragma unroll
        for (int r = 0; r < 4; ++r) p.h[r] = f2h(rd[r] + v[r]);
        *(uint2*)(outU + idx) = p.u;
      } else {                // EPI == 8: out = resid16(fp16) + v + bias -> f32
        f16x4 rh = *(const f16x4*)(residH + idx);
        f32x4 bb = *(const f32x4*)(bias + n);
        f32x4 o;
#pragma unroll
        for (int r = 0; r < 4; ++r) o[r] = (float)rh[r] + v[r] + bb[r];
        *(f32x4*)(outF + idx) = o;
      }
    }
}

// ---------- launch ----------
extern "C" void kernel_launch(void* const* d_in, const int* in_sizes, int n_in,
                              void* d_out, int out_size, void* d_ws, size_t ws_size,
                              hipStream_t stream)
{
  const float* x   = (const float*)d_in[0];
  const float* g1  = (const float*)d_in[1];
  const float* be1 = (const float*)d_in[2];
  const float* Wv  = (const float*)d_in[3];
  const float* Ww  = (const float*)d_in[4];
  const float* g2  = (const float*)d_in[5];
  const float* be2 = (const float*)d_in[6];
  const float* W1  = (const float*)d_in[7];
  const float* b1  = (const float*)d_in[8];
  const float* W2  = (const float*)d_in[9];
  const float* b2  = (const float*)d_in[10];
  float* out = (float*)d_out;

  char* ws = (char*)d_ws;
  // B=64, T=E=512, H=2048, M=B*T=32768. fp16 single-pass everywhere;
  // x1 kept in fp16 (error <= 6*2^-11 ~ 0.003, directly on output).
  u16* inp     = (u16*)(ws);                 // [0,32M)    LN1 -> pvx/scores
  u16* pvx     = (u16*)(ws + 33554432);      // [32,96M)   proj cols 0-511 | vx 512-1023 (ld 2048B)
  u16* scores16= (u16*)(ws + 100663296);     // [96,128M)  fp16 logits
  u16* attn    = (u16*)(ws + 134217728);     // [128,160M) softmax out
  u16* x1h     = (u16*)(ws + 167772160);     // [160,192M) fp16 x1 (lives to end)
  u16* h_in    = inp;                        // alias: written after inp dead
  u16* h_mid   = (u16*)(ws + 33554432);      // [32,160M): pvx/scores/attn dead by MLP1
  char* wb = ws + 201326592;                 // weights live whole run
  u16* WwT = (u16*)(wb);                     // rows 0-511 of merged B
  u16* WvT = (u16*)(wb + 524288);            // rows 512-1023 (contiguous)
  u16* W1T = (u16*)(wb + 1048576);
  u16* W2T = (u16*)(wb + 3145728);
  // total ws used: ~198 MB

  // all four weight transposes in ONE launch (f32 -> fp16, K-contiguous)
  transpose_all_kernel<<<2560, 256, 0, stream>>>(
      Ww, Wv, W1, W2, WwT, WvT, W1T, W2T);

  // LN1: x -> inp fp16
  ln_f16_kernel<<<8192, 256, 0, stream>>>(x, g1, be1, inp);

  // pvx = inp @ [Ww | Wv]  (N=1024; cols<512 plain -> proj, >=512 |.| -> vx)
  gemm8<6><<<dim3(4, 128, 1), 1024, 0, stream>>>(
      (const char*)inp, (const char*)inp, (const char*)inp, (const char*)inp,
      (const char*)WwT, (const char*)WwT, (const char*)WwT, (const char*)WwT,
      1024, 16, 1024, 1024, 0, 0, 0,
      nullptr, pvx, nullptr, nullptr, nullptr);

  // scores16[b,i,j] = sqrt((proj_i . inp_j)^2+eps) -> fp16 (batched)
  gemm8<0><<<dim3(2, 2, 64), 1024, 0, stream>>>(
      (const char*)pvx, (const char*)pvx, (const char*)pvx, (const char*)pvx,
      (const char*)inp, (const char*)inp, (const char*)inp, (const char*)inp,
      512, 16, 2048, 1024, 1048576, 524288, 262144,
      nullptr, scores16, nullptr, nullptr, nullptr);

  // softmax rows (fp16 in) -> attn fp16
  softmax_f16_kernel<<<8192, 256, 0, stream>>>(scores16, attn);

  // x1 = x + attn@vx^T -> x1h fp16 (batched; vx = pvx cols 512+)
  gemm8<7><<<dim3(2, 2, 64), 1024, 0, stream>>>(
      (const char*)attn, (const char*)attn, (const char*)attn, (const char*)attn,
      (const char*)pvx + 1024, (const char*)pvx + 1024, (const char*)pvx + 1024, (const char*)pvx + 1024,
      512, 16, 1024, 2048, 524288, 1048576, 262144,
      nullptr, x1h, x, nullptr, nullptr);

  // LN2: x1h (fp16) -> h_in fp16 (into dead inp)
  ln_h16_kernel<<<8192, 256, 0, stream>>>(x1h, g2, be2, h_in);

  // h_mid = gelu(h_in@W1 + b1) fp16
  gemm8<4><<<dim3(8, 128, 1), 1024, 0, stream>>>(
      (const char*)h_in, (const char*)h_in, (const char*)h_in, (const char*)h_in,
      (const char*)W1T, (const char*)W1T, (const char*)W1T, (const char*)W1T,
      2048, 16, 1024, 1024, 0, 0, 0,
      nullptr, h_mid, nullptr, nullptr, b1);

  // out = x1h + h_mid@W2 + b2  (K=2048 via 4 contiguous 1024B parts) -> f32
  gemm8<8><<<dim3(2, 128, 1), 1024, 0, stream>>>(
      (const char*)h_mid, (const char*)h_mid + 1024, (const char*)h_mid + 2048, (const char*)h_mid + 3072,
      (const char*)W2T, (const char*)W2T + 1024, (const char*)W2T + 2048, (const char*)W2T + 3072,
      512, 64, 4096, 4096, 0, 0, 0,
      out, nullptr, nullptr, x1h, b2);
}

// Round 18
// 342.412 us; speedup vs baseline: 6.4973x; 1.1128x over previous
//
#include <hip/hip_runtime.h>

using f16x8 = __attribute__((ext_vector_type(8))) _Float16;
using f16x4 = __attribute__((ext_vector_type(4))) _Float16;
using f32x4 = __attribute__((ext_vector_type(4))) float;
using u16 = unsigned short;
using u32 = unsigned int;

// ---------- helpers ----------
__device__ __forceinline__ u16 f2h(float f) {           // RNE f32->fp16 (v_cvt)
  union { _Float16 h; u16 u; } c;
  c.h = (_Float16)f;
  return c.u;
}
__device__ __forceinline__ uint4 pack8(const u16* h) {
  uint4 r;
  r.x = (u32)h[0] | ((u32)h[1] << 16);
  r.y = (u32)h[2] | ((u32)h[3] << 16);
  r.z = (u32)h[4] | ((u32)h[5] << 16);
  r.w = (u32)h[6] | ((u32)h[7] << 16);
  return r;
}
__device__ __forceinline__ float gelu_fast(float x) {   // == 0.5x(1+tanh(u)) exactly
  float u2 = 1.5957691216057308f * (x + 0.044715f * x * x * x);  // 2u
  return x / (1.0f + __expf(-u2));
}
__device__ __forceinline__ void gload16(const void* g, void* l) {
  __builtin_amdgcn_global_load_lds(
      (const __attribute__((address_space(1))) void*)g,
      (__attribute__((address_space(3))) void*)l, 16, 0, 0);
}

// ---------- fused weight transposes: all four [R,C] f32 -> [C,R] fp16 ----------
// One launch, 2560 blocks: [0,256) Ww 512x512; [256,512) Wv 512x512;
// [512,1536) W1 512x2048; [1536,2560) W2 2048x512. Each block does a 32x32 tile.
__global__ __launch_bounds__(256) void transpose_all_kernel(
    const float* __restrict__ Ww, const float* __restrict__ Wv,
    const float* __restrict__ W1, const float* __restrict__ W2,
    u16* __restrict__ WwT, u16* __restrict__ WvT,
    u16* __restrict__ W1T, u16* __restrict__ W2T)
{
  __shared__ float t[32][33];
  int id = blockIdx.x;
  const float* in; u16* out; int R, C, bx, by;
  if (id < 256)        { in = Ww; out = WwT; R = 512;  C = 512;  bx = id & 15; by = id >> 4; }
  else if (id < 512)   { id -= 256;  in = Wv; out = WvT; R = 512;  C = 512;  bx = id & 15; by = id >> 4; }
  else if (id < 1536)  { id -= 512;  in = W1; out = W1T; R = 512;  C = 2048; bx = id & 63; by = id >> 6; }
  else                 { id -= 1536; in = W2; out = W2T; R = 2048; C = 512;  bx = id & 15; by = id >> 4; }
  const int lx = threadIdx.x & 31, ly = threadIdx.x >> 5;
  const int c0 = bx << 5, r0 = by << 5;
  for (int i = ly; i < 32; i += 8)
    t[i][lx] = in[(long)(r0 + i) * C + c0 + lx];
  __syncthreads();
  for (int i = ly; i < 32; i += 8)
    out[(long)(c0 + i) * R + r0 + lx] = f2h(t[lx][i]);
}

// ---------- LayerNorm over rows of 512 f32 -> fp16 ----------
__global__ __launch_bounds__(256) void ln_f16_kernel(
    const float* __restrict__ x, const float* __restrict__ gamma,
    const float* __restrict__ beta, u16* __restrict__ outH)
{
  const int row  = (blockIdx.x << 2) + (threadIdx.x >> 6);
  const int lane = threadIdx.x & 63;
  const float* xr = x + (long)row * 512 + lane * 8;
  float v[8];
  *(float4*)&v[0] = *(const float4*)xr;
  *(float4*)&v[4] = *(const float4*)(xr + 4);
  float s = 0.f;
#pragma unroll
  for (int j = 0; j < 8; ++j) s += v[j];
#pragma unroll
  for (int o = 32; o; o >>= 1) s += __shfl_xor(s, o);
  const float mu = s * (1.0f / 512.0f);
  float q = 0.f;
#pragma unroll
  for (int j = 0; j < 8; ++j) { float d = v[j] - mu; q += d * d; }
#pragma unroll
  for (int o = 32; o; o >>= 1) q += __shfl_xor(q, o);
  const float rs = rsqrtf(q * (1.0f / 512.0f) + 1e-5f);
  float gv[8], bv[8];
  *(float4*)&gv[0] = *(const float4*)(gamma + lane * 8);
  *(float4*)&gv[4] = *(const float4*)(gamma + lane * 8 + 4);
  *(float4*)&bv[0] = *(const float4*)(beta + lane * 8);
  *(float4*)&bv[4] = *(const float4*)(beta + lane * 8 + 4);
  u16 hs[8];
#pragma unroll
  for (int j = 0; j < 8; ++j)
    hs[j] = f2h((v[j] - mu) * rs * gv[j] + bv[j]);
  *(uint4*)(outH + (long)row * 512 + lane * 8) = pack8(hs);
}

// ---------- LayerNorm over rows of 512 fp16 -> fp16 ----------
__global__ __launch_bounds__(256) void ln_h16_kernel(
    const u16* __restrict__ x, const float* __restrict__ gamma,
    const float* __restrict__ beta, u16* __restrict__ outH)
{
  const int row  = (blockIdx.x << 2) + (threadIdx.x >> 6);
  const int lane = threadIdx.x & 63;
  const f16x8 x8 = *(const f16x8*)(x + (long)row * 512 + lane * 8);
  float v[8];
#pragma unroll
  for (int j = 0; j < 8; ++j) v[j] = (float)x8[j];
  float s = 0.f;
#pragma unroll
  for (int j = 0; j < 8; ++j) s += v[j];
#pragma unroll
  for (int o = 32; o; o >>= 1) s += __shfl_xor(s, o);
  const float mu = s * (1.0f / 512.0f);
  float q = 0.f;
#pragma unroll
  for (int j = 0; j < 8; ++j) { float d = v[j] - mu; q += d * d; }
#pragma unroll
  for (int o = 32; o; o >>= 1) q += __shfl_xor(q, o);
  const float rs = rsqrtf(q * (1.0f / 512.0f) + 1e-5f);
  float gv[8], bv[8];
  *(float4*)&gv[0] = *(const float4*)(gamma + lane * 8);
  *(float4*)&gv[4] = *(const float4*)(gamma + lane * 8 + 4);
  *(float4*)&bv[0] = *(const float4*)(beta + lane * 8);
  *(float4*)&bv[4] = *(const float4*)(beta + lane * 8 + 4);
  u16 hs[8];
#pragma unroll
  for (int j = 0; j < 8; ++j)
    hs[j] = f2h((v[j] - mu) * rs * gv[j] + bv[j]);
  *(uint4*)(outH + (long)row * 512 + lane * 8) = pack8(hs);
}

// ---------- row softmax over 512 fp16 -> fp16 ----------
__global__ __launch_bounds__(256) void softmax_f16_kernel(
    const u16* __restrict__ scores, u16* __restrict__ attn)
{
  const int row  = (blockIdx.x << 2) + (threadIdx.x >> 6);
  const int lane = threadIdx.x & 63;
  const f16x8 v8 = *(const f16x8*)(scores + (long)row * 512 + lane * 8);
  float v[8];
#pragma unroll
  for (int j = 0; j < 8; ++j) v[j] = (float)v8[j];
  float m = v[0];
#pragma unroll
  for (int j = 1; j < 8; ++j) m = fmaxf(m, v[j]);
#pragma unroll
  for (int o = 32; o; o >>= 1) m = fmaxf(m, __shfl_xor(m, o));
  float e[8], s = 0.f;
#pragma unroll
  for (int j = 0; j < 8; ++j) { e[j] = __expf(v[j] - m); s += e[j]; }
#pragma unroll
  for (int o = 32; o; o >>= 1) s += __shfl_xor(s, o);
  const float inv = 1.0f / s;
  u16 h[8];
#pragma unroll
  for (int j = 0; j < 8; ++j) h[j] = f2h(e[j] * inv);
  *(uint4*)(attn + (long)row * 512 + lane * 8) = pack8(h);
}

// ---------- 256x256 16-wave NT GEMM, BK=64, fp16, 16x16x32 MFMA ----------
// (r12/r15 structure — the measured optimum; restored after r16/r17's BK=32
// 2-blocks/CU experiment was falsified: occupancy did not rise and 64B-row
// LDS geometry conflicts under every swizzle tried. 128B rows + s^(r&7) is
// the only measured conflict-free layout for this fragment pattern.)
// C[m,n] = sum_k A[m,k]*B[n,k]. K in NT tiles of 64; tile t uses part (t>>3).
// 1024 threads = 16 waves, 4/SIMD; wave owns 64x64 (wm=w>>2, wn=w&3);
// acc f32x4[4][4]. LDS 128KB dbuf; LDS[r][s] = G[r][s^(r&7)] via
// pre-swizzled global source. Loop: stage t+1 into buffer d^1, per kh:
// 4+4 ds_read_b128 + 16 MFMA; one __syncthreads() per tile.
// XCD-chunked block swizzle; swapped-operand MFMA -> wide stores.
// EPI: 0 fp16 sqrt(v^2+eps); 4 fp16 gelu(v+bias); 6 fp16, plain if
//      blockN<512 else sqrt(v^2+eps) [merged proj|vx]; 7 fp16(resid_f32+v);
//      8 f32 resid16(fp16)+v+bias [final out].
template<int EPI>
__global__ __launch_bounds__(1024) void gemm8(
    const char* A0, const char* A1, const char* A2, const char* A3,
    const char* B0, const char* B1, const char* B2, const char* B3,
    int N, int NT, int ldAb, int ldBb,
    long sAb, long sBb, long sC,
    float* __restrict__ outF, u16* __restrict__ outU,
    const float* __restrict__ resid, const u16* __restrict__ residH,
    const float* __restrict__ bias)
{
  __shared__ __align__(16) char lds[131072];
  const int tid = threadIdx.x;
  const int w = tid >> 6, l = tid & 63;
  const int wm = w >> 2, wn = w & 3;

  // XCD-chunked block swizzle (total %8 == 0 for all our launches)
  const int gx = gridDim.x, gy = gridDim.y;
  int flat = ((int)blockIdx.z * gy + (int)blockIdx.y) * gx + (int)blockIdx.x;
  const int total = gx * gy * (int)gridDim.z;
  flat = (flat & 7) * (total >> 3) + (flat >> 3);
  const int bx = flat % gx;
  int rem = flat / gx;
  const int by = rem % gy, bz = rem / gy;

  const long blockM = (long)by * 256;
  const long blockN = (long)bx * 256;
  const long za = (long)bz * sAb;
  const long zb = (long)bz * sBb;
  const char* a0p = A0 + za; const char* a1p = A1 + za;
  const char* a2p = A2 + za; const char* a3p = A3 + za;
  const char* b0p = B0 + zb; const char* b1p = B1 + zb;
  const char* b2p = B2 + zb; const char* b3p = B3 + zb;

  auto partA = [&](int t) { return t < 8 ? a0p : t < 16 ? a1p : t < 24 ? a2p : a3p; };
  auto partB = [&](int t) { return t < 8 ? b0p : t < 16 ? b1p : t < 24 ? b2p : b3p; };

  // staging: thread tid covers region row tid>>3 (0..127), slot tid&7;
  // global source slot pre-swizzled: (tid&7)^((tid>>3)&7).
  const long stgSw = ((tid & 7) ^ ((tid >> 3) & 7)) << 4;
  const long raA = (blockM + (tid >> 3)) * (long)ldAb + stgSw;
  const long raB = (blockN + (tid >> 3)) * (long)ldBb + stgSw;
  auto stageA = [&](int t, int h) {
    const char* s = partA(t) + (((long)(t & 7)) << 7) + raA + (long)h * 128 * ldAb;
    gload16(s, lds + ((t & 1) << 15) + (h << 14) + (tid << 4));
  };
  auto stageB = [&](int t, int h) {
    const char* s = partB(t) + (((long)(t & 7)) << 7) + raB + (long)h * 128 * ldBb;
    gload16(s, lds + 65536 + ((t & 1) << 15) + (h << 14) + (tid << 4));
  };

  f32x4 acc[4][4];
#pragma unroll
  for (int i = 0; i < 4; ++i)
#pragma unroll
    for (int j = 0; j < 4; ++j) acc[i][j] = (f32x4){0.f, 0.f, 0.f, 0.f};

  const int lr = l & 15, kg = l >> 4;
  const int xs = kg ^ (l & 7);
  const int po0 = (lr << 7) + (xs << 4);
  const int po1 = (lr << 7) + ((xs ^ 4) << 4);
  // wave's A quarter: region h = wm>>1, half (wm&1); B: h = wn>>1, half (wn&1)
  const char* aL = lds + ((wm >> 1) << 14) + ((wm & 1) << 13);
  const char* bL = lds + 65536 + ((wn >> 1) << 14) + ((wn & 1) << 13);

  f16x8 a[4], b[4];
  auto readA = [&](const char* p) {
#pragma unroll
    for (int mf = 0; mf < 4; ++mf) a[mf] = *(const f16x8*)(p + (mf << 11));
  };
  auto readB = [&](const char* p) {
#pragma unroll
    for (int nf = 0; nf < 4; ++nf) b[nf] = *(const f16x8*)(p + (nf << 11));
  };

#define MFMA16()                                                              \
  do {                                                                        \
    _Pragma("unroll")                                                         \
    for (int mf = 0; mf < 4; ++mf)                                            \
      _Pragma("unroll")                                                       \
      for (int nf = 0; nf < 4; ++nf)                                          \
        acc[mf][nf] = __builtin_amdgcn_mfma_f32_16x16x32_f16(                 \
            b[nf], a[mf], acc[mf][nf], 0, 0, 0);                              \
  } while (0)

  // prologue: stage tile 0
  stageA(0, 0); stageA(0, 1); stageB(0, 0); stageB(0, 1);
  __syncthreads();

  for (int t = 0; t < NT; ++t) {
    const int d = t & 1;
    const char* aD = aL + (d << 15);
    const char* bD = bL + (d << 15);
    if (t + 1 < NT) {
      stageA(t + 1, 0); stageA(t + 1, 1); stageB(t + 1, 0); stageB(t + 1, 1);
    }
    readA(aD + po0);
    readB(bD + po0);
    MFMA16();
    readA(aD + po1);
    readB(bD + po1);
    MFMA16();
    if (t + 1 < NT) __syncthreads();
  }
#undef MFMA16

  // ---- epilogue (swapped layout): m = ..+lr, n = ..+kg*4+r -> wide stores
  const long cb = (long)bz * sC;
  const int m0 = (int)blockM + wm * 64 + lr;
  const int n0 = (int)blockN + wn * 64 + (kg << 2);
  const bool vabs = (blockN >= 512);   // for EPI 6 (merged proj|vx)
#pragma unroll
  for (int mi = 0; mi < 4; ++mi)
#pragma unroll
    for (int ni = 0; ni < 4; ++ni) {
      const int m = m0 + (mi << 4);
      const int n = n0 + (ni << 4);
      const long idx = cb + (long)m * N + n;
      f32x4 v = acc[mi][ni];
      if (EPI == 0) {
        union { u16 h[4]; uint2 u; } p;
#pragma unroll
        for (int r = 0; r < 4; ++r) p.h[r] = f2h(sqrtf(v[r] * v[r] + 1e-8f));
        *(uint2*)(outU + idx) = p.u;
      } else if (EPI == 4) {
        f32x4 bb = *(const f32x4*)(bias + n);
        union { u16 h[4]; uint2 u; } p;
#pragma unroll
        for (int r = 0; r < 4; ++r) p.h[r] = f2h(gelu_fast(v[r] + bb[r]));
        *(uint2*)(outU + idx) = p.u;
      } else if (EPI == 6) {  // merged proj|vx
        union { u16 h[4]; uint2 u; } p;
#pragma unroll
        for (int r = 0; r < 4; ++r)
          p.h[r] = f2h(vabs ? sqrtf(v[r] * v[r] + 1e-8f) : v[r]);
        *(uint2*)(outU + idx) = p.u;
      } else if (EPI == 7) {  // x1 = resid(f32) + v -> fp16
        f32x4 rd = *(const f32x4*)(resid + idx);
        union { u16 h[4]; uint2 u; } p;
#pragma unroll
        for (int r = 0; r < 4; ++r) p.h[r] = f2h(rd[r] + v[r]);
        *(uint2*)(outU + idx) = p.u;
      } else {                // EPI == 8: out = resid16(fp16) + v + bias -> f32
        f16x4 rh = *(const f16x4*)(residH + idx);
        f32x4 bb = *(const f32x4*)(bias + n);
        f32x4 o;
#pragma unroll
        for (int r = 0; r < 4; ++r) o[r] = (float)rh[r] + v[r] + bb[r];
        *(f32x4*)(outF + idx) = o;
      }
    }
}

// ---------- launch ----------
extern "C" void kernel_launch(void* const* d_in, const int* in_sizes, int n_in,
                              void* d_out, int out_size, void* d_ws, size_t ws_size,
                              hipStream_t stream)
{
  const float* x   = (const float*)d_in[0];
  const float* g1  = (const float*)d_in[1];
  const float* be1 = (const float*)d_in[2];
  const float* Wv  = (const float*)d_in[3];
  const float* Ww  = (const float*)d_in[4];
  const float* g2  = (const float*)d_in[5];
  const float* be2 = (const float*)d_in[6];
  const float* W1  = (const float*)d_in[7];
  const float* b1  = (const float*)d_in[8];
  const float* W2  = (const float*)d_in[9];
  const float* b2  = (const float*)d_in[10];
  float* out = (float*)d_out;

  char* ws = (char*)d_ws;
  // B=64, T=E=512, H=2048, M=B*T=32768. fp16 single-pass everywhere;
  // x1 kept in fp16 (error <= 6*2^-11 ~ 0.003, directly on output).
  u16* inp     = (u16*)(ws);                 // [0,32M)    LN1 -> pvx/scores
  u16* pvx     = (u16*)(ws + 33554432);      // [32,96M)   proj cols 0-511 | vx 512-1023 (ld 2048B)
  u16* scores16= (u16*)(ws + 100663296);     // [96,128M)  fp16 logits
  u16* attn    = (u16*)(ws + 134217728);     // [128,160M) softmax out
  u16* x1h     = (u16*)(ws + 167772160);     // [160,192M) fp16 x1 (lives to end)
  u16* h_in    = inp;                        // alias: written after inp dead
  u16* h_mid   = (u16*)(ws + 33554432);      // [32,160M): pvx/scores/attn dead by MLP1
  char* wb = ws + 201326592;                 // weights live whole run
  u16* WwT = (u16*)(wb);                     // rows 0-511 of merged B
  u16* WvT = (u16*)(wb + 524288);            // rows 512-1023 (contiguous)
  u16* W1T = (u16*)(wb + 1048576);
  u16* W2T = (u16*)(wb + 3145728);
  // total ws used: ~198 MB

  // all four weight transposes in ONE launch (f32 -> fp16, K-contiguous)
  transpose_all_kernel<<<2560, 256, 0, stream>>>(
      Ww, Wv, W1, W2, WwT, WvT, W1T, W2T);

  // LN1: x -> inp fp16
  ln_f16_kernel<<<8192, 256, 0, stream>>>(x, g1, be1, inp);

  // pvx = inp @ [Ww | Wv]  (N=1024; cols<512 plain -> proj, >=512 |.| -> vx)
  gemm8<6><<<dim3(4, 128, 1), 1024, 0, stream>>>(
      (const char*)inp, (const char*)inp, (const char*)inp, (const char*)inp,
      (const char*)WwT, (const char*)WwT, (const char*)WwT, (const char*)WwT,
      1024, 8, 1024, 1024, 0, 0, 0,
      nullptr, pvx, nullptr, nullptr, nullptr);

  // scores16[b,i,j] = sqrt((proj_i . inp_j)^2+eps) -> fp16 (batched)
  gemm8<0><<<dim3(2, 2, 64), 1024, 0, stream>>>(
      (const char*)pvx, (const char*)pvx, (const char*)pvx, (const char*)pvx,
      (const char*)inp, (const char*)inp, (const char*)inp, (const char*)inp,
      512, 8, 2048, 1024, 1048576, 524288, 262144,
      nullptr, scores16, nullptr, nullptr, nullptr);

  // softmax rows (fp16 in) -> attn fp16
  softmax_f16_kernel<<<8192, 256, 0, stream>>>(scores16, attn);

  // x1 = x + attn@vx^T -> x1h fp16 (batched; vx = pvx cols 512+)
  gemm8<7><<<dim3(2, 2, 64), 1024, 0, stream>>>(
      (const char*)attn, (const char*)attn, (const char*)attn, (const char*)attn,
      (const char*)pvx + 1024, (const char*)pvx + 1024, (const char*)pvx + 1024, (const char*)pvx + 1024,
      512, 8, 1024, 2048, 524288, 1048576, 262144,
      nullptr, x1h, x, nullptr, nullptr);

  // LN2: x1h (fp16) -> h_in fp16 (into dead inp)
  ln_h16_kernel<<<8192, 256, 0, stream>>>(x1h, g2, be2, h_in);

  // h_mid = gelu(h_in@W1 + b1) fp16
  gemm8<4><<<dim3(8, 128, 1), 1024, 0, stream>>>(
      (const char*)h_in, (const char*)h_in, (const char*)h_in, (const char*)h_in,
      (const char*)W1T, (const char*)W1T, (const char*)W1T, (const char*)W1T,
      2048, 8, 1024, 1024, 0, 0, 0,
      nullptr, h_mid, nullptr, nullptr, b1);

  // out = x1h + h_mid@W2 + b2  (K=2048 via 4 contiguous parts) -> d_out f32
  gemm8<8><<<dim3(2, 128, 1), 1024, 0, stream>>>(
      (const char*)h_mid, (const char*)h_mid + 1024, (const char*)h_mid + 2048, (const char*)h_mid + 3072,
      (const char*)W2T, (const char*)W2T + 1024, (const char*)W2T + 2048, (const char*)W2T + 3072,
      512, 32, 4096, 4096, 0, 0, 0,
      out, nullptr, nullptr, x1h, b2);
}